// Round 7
// baseline (103.030 us; speedup 1.0000x reference)
//
#include <hip/hip_runtime.h>
#include <hip/hip_bf16.h>

typedef __attribute__((ext_vector_type(8))) short short8;   // 8 bf16 (4 VGPRs)
typedef __attribute__((ext_vector_type(4))) float f32x4;
typedef unsigned int uint;
typedef __attribute__((ext_vector_type(4))) uint uint4v;

#define AS1 __attribute__((address_space(1)))
#define AS3 __attribute__((address_space(3)))

// ws: Rp4 [0,1MB) | Qp4 [1MB,1.25MB)   (xph ELIMINATED)
#define QB_OFF  (1u << 20)
// Rp4: [s 0..63][kg 0..3][col 0..255]*16B ; holds R[col][k=s*32+kg*8+e]
//      (k-order: g=k>>7 window, c=k&127; f=c*16+g)
// Qp4: [ks 0..7][col 0..511][cu 0..3]*16B ; Q[col][ks*32+cu*8+e]

__device__ __forceinline__ uint bf16r(float f) {
    uint u = __float_as_uint(f);
    u += 0x7FFFu + ((u >> 16) & 1u);
    return u >> 16;
}
__device__ __forceinline__ uint pk2(float lo, float hi) {
    return bf16r(lo) | (bf16r(hi) << 16);
}

// ---------------- prep: R and Q repack only (x round-trip eliminated) ----------------
__global__ __launch_bounds__(256) void prep_kernel(
    const float* __restrict__ Q, const float* __restrict__ R,
    char* __restrict__ Rp4, char* __restrict__ Qp4)
{
    const int bid = blockIdx.x, tid = threadIdx.x;
    if (bid < 256) {                        // R -> Rp4[s][kg][col] (linear dst)
        int g = bid * 256 + tid;            // 0..65535
        int s = g >> 10, rem = g & 1023;
        int kgu = rem >> 8, col = rem & 255;
        // k = s*32 + kgu*8 + e ; g_win = s>>2 ; c = (s&3)*32 + kgu*8 + e ; f = c*16 + g_win
        const float* src = R + (size_t)col * 2048 + (((s & 3) * 32 + kgu * 8) * 16 + (s >> 2));
        uint pw[4];
        #pragma unroll
        for (int m = 0; m < 4; ++m)
            pw[m] = pk2(src[(2 * m) * 16], src[(2 * m + 1) * 16]);
        uint4v q4 = { pw[0], pw[1], pw[2], pw[3] };
        *(uint4v*)(Rp4 + (size_t)g * 16) = q4;
    } else {                                 // Q -> Qp4[ks][col][cu] (linear dst)
        int g = (bid - 256) * 256 + tid;    // 0..16383
        int ks = g >> 11, p = g & 2047;
        int col = p >> 2, cu = p & 3;
        const float4* s = (const float4*)(Q + (size_t)col * 256 + ks * 32 + cu * 8);
        float4 a = s[0], b = s[1];
        uint4v q4 = { pk2(a.x, a.y), pk2(a.z, a.w), pk2(b.x, b.y), pk2(b.z, b.w) };
        *(uint4v*)(Qp4 + (size_t)ks * 32768 + p * 16) = q4;
    }
}

// ---------------- fused: BM=64 x BN=256, 512 thr / 8 waves (2M x 4N), barrier-free gemm1 ----------------
// Block (n, vt): builds LDS xblock[ri 0..5][wc 0..71 pad][c 0..127] bf16 (stride 272B/wc,
// 17952B/ri, 107712B total) directly from NCHW fp32 x (coalesced 64B runs + in-LDS transpose),
// then gemm1 = 16 groups (one 3x3-window offset each, 4 K-steps): B(R) global->regs double-
// buffered with explicit vmcnt(16) ledger (R0-proven), A via conflict-free ds_read_b128 from
// read-only xblock -> ZERO barriers in gemm1. Two __syncthreads total (xblock build, ttile).
// gemm2 + direct stores: R4's proven mappings (WRITE_SIZE clean 64MB).
__global__ __launch_bounds__(512, 2) void fused_kernel(
    const float* __restrict__ x, const char* __restrict__ Rp4,
    const char* __restrict__ Qp4, float* __restrict__ out)
{
    extern __shared__ __align__(16) char lds[];

    const int blk = blockIdx.x;
    const int b = (blk & 7) * 64 + (blk >> 3);  // XCD-contiguous swizzle (512%8==0)
    const int n = b >> 4, vt = b & 15;          // block: ov rows {2vt,2vt+1} (out h 4vt..4vt+3)
    const int tid = threadIdx.x;
    const int wave = tid >> 6, lane = tid & 63;
    const int lr = lane & 15, kg = lane >> 4;
    const int wm = wave >> 2, wn = wave & 3;    // gemm1: pos-half wm*32, rank cols wn*64

    // ---- build xblock: x[n][c][hh][w] fp32 -> bf16 [ri][wc][c], c-pairs packed as u32 ----
    {
        const int cpair = tid & 63, seg = (tid >> 6) & 3, half = tid >> 8;
        const float* xb0 = x + ((size_t)n * 128 + 2 * cpair) * 4096;   // + hh*64 + w
        #pragma unroll
        for (int rr = 0; rr < 3; ++rr) {
            const int ri = half * 3 + rr;
            const int hh = 4 * vt - 1 + ri;
            const bool val = (hh >= 0) && (hh < 64);
            const int hhc = val ? hh : 0;
            const float4* pa = (const float4*)(xb0 + (size_t)hhc * 64 + seg * 16);
            const float4* pb = (const float4*)(xb0 + 4096 + (size_t)hhc * 64 + seg * 16);
            char* dst = lds + ri * 17952 + (seg * 16 + 1) * 272 + cpair * 4;
            #pragma unroll
            for (int qq = 0; qq < 4; ++qq) {
                float4 a = pa[qq], c = pb[qq];
                uint w0 = val ? pk2(a.x, c.x) : 0u;
                uint w1 = val ? pk2(a.y, c.y) : 0u;
                uint w2 = val ? pk2(a.z, c.z) : 0u;
                uint w3 = val ? pk2(a.w, c.w) : 0u;
                char* d = dst + qq * 4 * 272;
                *(uint*)(d)           = w0;
                *(uint*)(d + 272)     = w1;
                *(uint*)(d + 2 * 272) = w2;
                *(uint*)(d + 3 * 272) = w3;
            }
        }
        // w-borders wc=0 and wc=65 (768 u32 zeros)
        #pragma unroll
        for (int it = 0; it < 2; ++it) {
            int idx = it * 512 + tid;
            if (idx < 768) {
                int side = idx & 1, cp = (idx >> 1) & 63, ri = idx >> 7;
                *(uint*)(lds + ri * 17952 + side * 65 * 272 + cp * 4) = 0u;
            }
        }
    }
    __syncthreads();

    // ---- gemm1: 16 groups x 4 K-steps, zero barriers ----
    // A-frag (mf 0..1, cu 0..3): addr = (2wm+i)*17952 + (2*(mf*16+lr)+j)*272 + (cu*4+kg)*16
    const int aw = (2 * wm) * 17952 + (2 * lr) * 272 + kg * 16;
    // B-frag (cu,nf): Rp4 + (g*4+cu)*16384 + kg*4096 + (wn*64+nf*16+lr)*16
    const char* rb = Rp4 + kg * 4096 + (wn * 64 + lr) * 16;

    f32x4 acc[2][4];
    #pragma unroll
    for (int i = 0; i < 2; ++i)
        #pragma unroll
        for (int j = 0; j < 4; ++j) acc[i][j] = (f32x4)0.f;

    short8 bA[16], bB[16];

#define BLOAD(dst_, g_) { _Pragma("unroll") for (int cu = 0; cu < 4; ++cu)              \
        _Pragma("unroll") for (int nf = 0; nf < 4; ++nf)                                \
            dst_[cu * 4 + nf] = *(const short8*)(rb + (size_t)((g_) * 4 + cu) * 16384 + nf * 256); }

#define WAITG(Nstr) { __builtin_amdgcn_sched_barrier(0);                                \
        asm volatile("s_waitcnt vmcnt(" Nstr ") lgkmcnt(0)" ::: "memory");              \
        __builtin_amdgcn_sched_barrier(0); }

#define MFMAG(bf_, g_) {                                                                \
        const int ao_ = aw + ((g_) >> 2) * 17952 + ((g_) & 3) * 272;                    \
        short8 afg[8];                                                                  \
        _Pragma("unroll") for (int cu = 0; cu < 4; ++cu)                                \
            _Pragma("unroll") for (int mf = 0; mf < 2; ++mf)                            \
                afg[cu * 2 + mf] = *(const short8*)(lds + ao_ + mf * 8704 + cu * 64);   \
        WAITG(NW_)                                                                      \
        __builtin_amdgcn_s_setprio(1);                                                  \
        _Pragma("unroll") for (int cu = 0; cu < 4; ++cu)                                \
            _Pragma("unroll") for (int nf = 0; nf < 4; ++nf)                            \
                _Pragma("unroll") for (int mf = 0; mf < 2; ++mf)                        \
                    acc[mf][nf] = __builtin_amdgcn_mfma_f32_16x16x32_bf16(              \
                        afg[cu * 2 + mf], bf_[cu * 4 + nf], acc[mf][nf], 0, 0, 0);      \
        __builtin_amdgcn_s_setprio(0); }

    BLOAD(bA, 0)
    #pragma unroll
    for (int g = 0; g < 16; g += 2) {
        BLOAD(bB, g + 1)
        #define NW_ "16"
        MFMAG(bA, g)
        #undef NW_
        if (g < 14) {
            BLOAD(bA, g + 2)
            #define NW_ "16"
            MFMAG(bB, g + 1)
            #undef NW_
        } else {
            #define NW_ "0"
            MFMAG(bB, g + 1)
            #undef NW_
        }
    }

    __syncthreads();                         // all waves done reading xblock

    // ---- ttile: acc -> bf16 [ru 0..31][pos 0..63]*16B at lds+0 ; (ru,pos) = T[pos][ru*8+e] ----
    // ru = wn*8+nf*2+(lr>>3) ; pos = wm*32+mf*16+kg*4+r ; e = lr&7
    {
        const int t0 = (wn * 8 + (lr >> 3)) * 1024 + wm * 512 + (lr & 7) * 2;
        #pragma unroll
        for (int mf = 0; mf < 2; ++mf)
            #pragma unroll
            for (int nf = 0; nf < 4; ++nf)
                #pragma unroll
                for (int r = 0; r < 4; ++r)
                    *(ushort*)(lds + t0 + nf * 2048 + (mf * 16 + kg * 4 + r) * 16) =
                        (ushort)bf16r(acc[mf][nf][r]);
    }
    __syncthreads();

    // ---- gemm2: Y[64][512] = ttile @ Q^T ; per-wave global Q (L2-hot), barrier-free ----
    const int a2 = kg * 1024 + wm * 512 + lr * 16;   // + ks*4096 + u*256
    int qoff[8];
    #pragma unroll
    for (int nf = 0; nf < 8; ++nf)
        qoff[nf] = ((wn >> 1) * 256 + (nf >> 2) * 128 + (wn & 1) * 64 + (nf & 3) * 16 + lr) * 64 + kg * 16;
    const int si = wn >> 1, ochalf = wn & 1;

    f32x4 a2c[2][8];
    #pragma unroll
    for (int u = 0; u < 2; ++u)
        #pragma unroll
        for (int j = 0; j < 8; ++j) a2c[u][j] = (f32x4)0.f;
    #pragma unroll
    for (int ks = 0; ks < 8; ++ks) {
        short8 af2[2];
        af2[0] = *(const short8*)(lds + ks * 4096 + a2);
        af2[1] = *(const short8*)(lds + ks * 4096 + a2 + 256);
        #pragma unroll
        for (int nf = 0; nf < 8; ++nf) {
            const short8 bq = *(const short8*)(Qp4 + (size_t)ks * 32768 + qoff[nf]);
            a2c[0][nf] = __builtin_amdgcn_mfma_f32_16x16x32_bf16(af2[0], bq, a2c[0][nf], 0, 0, 0);
            a2c[1][nf] = __builtin_amdgcn_mfma_f32_16x16x32_bf16(af2[1], bq, a2c[1][nf], 0, 0, 0);
        }
    }

    // ---- direct stores (R4-proven clean-64MB pattern) ----
    // pos = wm*32 + u*16 + kg*4 + r -> h = 4vt + 2wm + si ; w = u*32 + kg*8 + 2r + sj
    const int h = 4 * vt + 2 * wm + si;
    float* ob = out + (size_t)n * 524288 + (size_t)h * 64;
    #pragma unroll
    for (int u = 0; u < 2; ++u)
        #pragma unroll
        for (int q = 0; q < 4; ++q) {
            const int oc = ochalf * 64 + q * 16 + lr;
            float* o2 = ob + (size_t)oc * 4096 + u * 32 + kg * 8;
            f32x4 v0 = { a2c[u][q][0], a2c[u][4 + q][0], a2c[u][q][1], a2c[u][4 + q][1] };
            f32x4 v1 = { a2c[u][q][2], a2c[u][4 + q][2], a2c[u][q][3], a2c[u][4 + q][3] };
            *(f32x4*)(o2) = v0;
            *(f32x4*)(o2 + 4) = v1;
        }
}

extern "C" void kernel_launch(void* const* d_in, const int* in_sizes, int n_in,
                              void* d_out, int out_size, void* d_ws, size_t ws_size,
                              hipStream_t stream) {
    const float* x = (const float*)d_in[0];
    const float* Q = (const float*)d_in[1];
    const float* R = (const float*)d_in[2];
    float* out = (float*)d_out;

    char* ws = (char*)d_ws;
    char* Rp4 = ws;
    char* Qp4 = ws + QB_OFF;

    prep_kernel<<<320, 256, 0, stream>>>(Q, R, Rp4, Qp4);
    fused_kernel<<<512, 512, 107712, stream>>>(x, Rp4, Qp4, out);
}

// Round 8
// 80.238 us; speedup vs baseline: 1.2841x; 1.2841x over previous
//
#include <hip/hip_runtime.h>
#include <hip/hip_bf16.h>

typedef __attribute__((ext_vector_type(8))) short short8;   // 8 bf16 (4 VGPRs)
typedef __attribute__((ext_vector_type(4))) float f32x4;
typedef unsigned int uint;
typedef __attribute__((ext_vector_type(4))) uint uint4v;

#define AS1 __attribute__((address_space(1)))
#define AS3 __attribute__((address_space(3)))

// ws: Rp4 [0,1MB) | Qp4 [1MB,1.25MB) | xph [1.25MB, +34.1MB)
#define QB_OFF  (1u << 20)
#define XPH_OFF (1310720u)
// xph byte addr: n*1115136 + row*16896 + col*256 + c*2   (row,col in 0..65, c in 0..127)
// Rp4: [s 0..63][cu 0..3][col 0..255]*16B ; holds R[col][k=s*32+cu*8+e]
//      (k-order: g=k>>7 window, c=k&127; f=c*16+g)
// Qp4: [ks 0..7][col 0..511][cu 0..3]*16B ; Q[col][ks*32+cu*8+e]

__device__ __forceinline__ uint bf16r(float f) {
    uint u = __float_as_uint(f);
    u += 0x7FFFu + ((u >> 16) & 1u);
    return u >> 16;
}
__device__ __forceinline__ uint pk2(float lo, float hi) {
    return bf16r(lo) | (bf16r(hi) << 16);
}

// ---------------- prep (R4-proven, verbatim): NHWC bf16 xph, [s][cu][col] Rp4, Qp4 ----------------
__global__ __launch_bounds__(256) void prep_kernel(
    const float* __restrict__ x, const float* __restrict__ Q, const float* __restrict__ R,
    char* __restrict__ Rp4, char* __restrict__ Qp4, char* __restrict__ xph)
{
    const int bid = blockIdx.x, tid = threadIdx.x;
    if (bid < 2048) {                       // transpose: n = bid>>6, h = bid&63
        __shared__ float xt[128 * 65];
        const int n = bid >> 6, h = bid & 63;
        {
            const int c = tid >> 1, half = tid & 1;
            const float4* src = (const float4*)(x + (((size_t)(n * 128 + c) * 64 + h) * 64 + half * 32));
            #pragma unroll
            for (int q = 0; q < 8; ++q) {
                float4 v = src[q];
                float* d = &xt[c * 65 + half * 32 + q * 4];
                d[0] = v.x; d[1] = v.y; d[2] = v.z; d[3] = v.w;
            }
        }
        __syncthreads();
        {
            const int w = tid >> 2, cq = tid & 3;
            uint pw[16];
            #pragma unroll
            for (int m = 0; m < 16; ++m)
                pw[m] = pk2(xt[(cq * 32 + 2 * m) * 65 + w], xt[(cq * 32 + 2 * m + 1) * 65 + w]);
            char* dst = xph + (size_t)n * 1115136 + (size_t)(h + 1) * 16896 + (w + 1) * 256 + cq * 64;
            #pragma unroll
            for (int i = 0; i < 4; ++i) {
                uint4v q4 = { pw[4 * i], pw[4 * i + 1], pw[4 * i + 2], pw[4 * i + 3] };
                *(uint4v*)(dst + i * 16) = q4;
            }
        }
        if (tid < 32) {
            int side = tid >> 4, e = tid & 15;
            uint4v z = {0, 0, 0, 0};
            *(uint4v*)(xph + (size_t)n * 1115136 + (size_t)(h + 1) * 16896 + side * 65 * 256 + e * 16) = z;
        }
        if (h == 0) {
            uint4v z = {0, 0, 0, 0};
            #pragma unroll
            for (int it = 0; it < 9; ++it) {
                int idx = tid + it * 256;
                if (idx < 2112) {
                    int rr = (idx >= 1056) ? 65 : 0;
                    int jj = idx - (rr ? 1056 : 0);
                    int col = jj >> 4, e = jj & 15;
                    *(uint4v*)(xph + (size_t)n * 1115136 + (size_t)rr * 16896 + col * 256 + e * 16) = z;
                }
            }
        }
    } else if (bid < 2304) {                // R -> Rp4[s][cu][col] (linear dst)
        int g = (bid - 2048) * 256 + tid;
        int s = g >> 10, rem = g & 1023;
        int cu = rem >> 8, col = rem & 255;
        const float* src = R + (size_t)col * 2048 + (((s & 3) * 32 + cu * 8) * 16 + (s >> 2));
        uint pw[4];
        #pragma unroll
        for (int m = 0; m < 4; ++m)
            pw[m] = pk2(src[(2 * m) * 16], src[(2 * m + 1) * 16]);
        uint4v q4 = { pw[0], pw[1], pw[2], pw[3] };
        *(uint4v*)(Rp4 + (size_t)g * 16) = q4;
    } else {                                 // Q -> Qp4[ks][col][cu] (linear dst)
        int g = (bid - 2304) * 256 + tid;
        int ks = g >> 11, p = g & 2047;
        int col = p >> 2, cu = p & 3;
        const float4* s = (const float4*)(Q + (size_t)col * 256 + ks * 32 + cu * 8);
        float4 a = s[0], b = s[1];
        uint4v q4 = { pk2(a.x, a.y), pk2(a.z, a.w), pk2(b.x, b.y), pk2(b.z, b.w) };
        *(uint4v*)(Qp4 + (size_t)ks * 32768 + p * 16) = q4;
    }
}

// ---------------- fused: BM=128 x BN=256, 512 thr / 8 waves, m201-mechanics gemm1 ----------------
// 64 phases (K=32 each), 5-deep rotation: A 5x8KB [0,40960) | B 5x16KB [40960,122880).
// Phase p: STAGE(p+4) ; ds_read frags(p+1)->regNext ; lgkmcnt(8) [regCur ready] ;
//          setprio 16xMFMA(regCur) setprio ; vmcnt(6)+s_barrier  [ONE barrier/phase].
// Ledger: end-of-p barrier drains stage(p+2) (in flight p+2,p+3,p+4 = 9 -> keep 6); the
// frags(p+2) read happens at phase p+1 AFTER that barrier -> cross-wave DMA visibility.
// slab[(p+4)%5] was last read at phase p-2 -> 2 barriers before re-issue. vmcnt never 0
// until the tail. Frag read-ahead + sched_barrier pins give the m201 interleave:
// while one wave MFMAs, co-resident waves are in ds_read/STAGE -> DS & MFMA pipes co-issue.
__global__ __launch_bounds__(512, 2) void fused_kernel(
    const char* __restrict__ xph, const char* __restrict__ Rp4,
    const char* __restrict__ Qp4, float* __restrict__ out)
{
    extern __shared__ __align__(16) char lds[];

    const int blk = blockIdx.x;
    const int b = (blk & 7) * 32 + (blk >> 3);  // XCD-contiguous swizzle (256%8==0)
    const int n = b >> 3, vt = b & 7;           // block: out rows 8vt..8vt+7
    const int tid = threadIdx.x;
    const int wave = tid >> 6, lane = tid & 63;
    const int lr = lane & 15, kg = lane >> 4;
    const int wm = wave >> 2, wn = wave & 3;    // rows wm*64.., rank cols wn*64..

    const char* xbase = xph + (size_t)n * 1115136;
    const int u16 = tid * 16;

    // X stage (R6-proven): dest unit tid -> [cu=tid>>7][pos=tid&127]
    const int xc = (8 * vt + 2 * ((tid >> 5) & 3)) * 16896 + (tid & 31) * 512 + (tid >> 7) * 16;

    // frag bases (R6-proven, conflict-free: quarter-wave reads 256B contiguous)
    const int a0 = kg * 2048 + (wm * 64 + lr) * 16;   // + mf*256, in A slab
    const int b0 = kg * 4096 + (wn * 64 + lr) * 16;   // + nf*256, in B slab

#define STAGE(t_) { \
        __builtin_amdgcn_global_load_lds( \
            (const AS1 void*)(xbase + xc + ((t_) >> 4) * 16896 + (((t_) >> 2) & 3) * 256 + ((t_) & 3) * 64), \
            (AS3 void*)(lds + ((t_) % 5) * 8192 + u16), 16, 0, 0); \
        _Pragma("unroll") for (int q = 0; q < 2; ++q) \
            __builtin_amdgcn_global_load_lds( \
                (const AS1 void*)(Rp4 + (size_t)(t_) * 16384 + q * 8192 + u16), \
                (AS3 void*)(lds + 40960 + ((t_) % 5) * 16384 + q * 8192 + u16), 16, 0, 0); }

#define FRAGS(af_, bf_, t_) { \
        const char* xs_ = lds + ((t_) % 5) * 8192; \
        const char* bs_ = lds + 40960 + ((t_) % 5) * 16384; \
        _Pragma("unroll") for (int mf = 0; mf < 4; ++mf) \
            af_[mf] = *(const short8*)(xs_ + a0 + mf * 256); \
        _Pragma("unroll") for (int nf = 0; nf < 4; ++nf) \
            bf_[nf] = *(const short8*)(bs_ + b0 + nf * 256); }

#define MFMA16(af_, bf_) { \
        __builtin_amdgcn_s_setprio(1); \
        _Pragma("unroll") for (int nf = 0; nf < 4; ++nf) \
            _Pragma("unroll") for (int mf = 0; mf < 4; ++mf) \
                acc[mf][nf] = __builtin_amdgcn_mfma_f32_16x16x32_bf16(af_[mf], bf_[nf], acc[mf][nf], 0, 0, 0); \
        __builtin_amdgcn_s_setprio(0); }

#define SB __builtin_amdgcn_sched_barrier(0);
#define LGKM(Nstr) { SB asm volatile("s_waitcnt lgkmcnt(" Nstr ")" ::: "memory"); SB }
#define ENDBAR(Nstr) { SB asm volatile("s_waitcnt vmcnt(" Nstr ")\n\ts_barrier" ::: "memory"); SB }

    f32x4 acc[4][4];
    #pragma unroll
    for (int i = 0; i < 4; ++i)
        #pragma unroll
        for (int j = 0; j < 4; ++j) acc[i][j] = (f32x4)0.f;

    short8 afA[4], bfA[4], afB[4], bfB[4];

    // prologue: stages 0..3 in flight (12 loads); drain 0,1 (phase0 reads frags(1)); read frags(0)
    STAGE(0) STAGE(1) STAGE(2) STAGE(3)
    ENDBAR("6")
    FRAGS(afA, bfA, 0)

    // ---- gemm1: 64 phases, steady p=0..59 ----
    #pragma unroll
    for (int p = 0; p < 60; p += 2) {
        STAGE(p + 4)
        FRAGS(afB, bfB, p + 1)
        LGKM("8")
        MFMA16(afA, bfA)
        ENDBAR("6")
        STAGE(p + 5)
        FRAGS(afA, bfA, p + 2)
        LGKM("8")
        MFMA16(afB, bfB)
        ENDBAR("6")
    }
    // p=60: in flight 62,63 after drain -> vmcnt(3)
    FRAGS(afB, bfB, 61)
    LGKM("8")
    MFMA16(afA, bfA)
    ENDBAR("3")
    // p=61: drain 63 -> vmcnt(0)
    FRAGS(afA, bfA, 62)
    LGKM("8")
    MFMA16(afB, bfB)
    ENDBAR("0")
    // p=62
    FRAGS(afB, bfB, 63)
    LGKM("8")
    MFMA16(afA, bfA)
    SB asm volatile("s_barrier" ::: "memory"); SB
    // p=63
    LGKM("0")
    MFMA16(afB, bfB)

    __syncthreads();                         // all waves done with slabs; ttile overlays

    // ---- ttile (R6-proven): [ru 0..31][pos 0..127]*16B at lds+0 ; (ru,pos) = T[pos][ru*8+e] ----
    {
        const int t0 = (wn * 8 + (lr >> 3)) * 2048 + wm * 1024 + (lr & 7) * 2;
        #pragma unroll
        for (int mf = 0; mf < 4; ++mf)
            #pragma unroll
            for (int nf = 0; nf < 4; ++nf)
                #pragma unroll
                for (int r = 0; r < 4; ++r)
                    *(ushort*)(lds + t0 + nf * 4096 + (mf * 16 + kg * 4 + r) * 16) =
                        (ushort)bf16r(acc[mf][nf][r]);
    }
    __syncthreads();

    // ---- gemm2 (R6-proven): Y[128][512] = ttile @ Q^T ; global Q (L2-hot), barrier-free ----
    const int a2 = kg * 2048 + wm * 1024 + lr * 16;   // + ks*8192 + mf*256
    int qoff[8];
    #pragma unroll
    for (int nf = 0; nf < 8; ++nf)
        qoff[nf] = ((wn >> 1) * 256 + (nf >> 2) * 128 + (wn & 1) * 64 + (nf & 3) * 16 + lr) * 64 + kg * 16;
    const int si = wn >> 1, ochalf = wn & 1;

    f32x4 acc2[4][8];
    #pragma unroll
    for (int i = 0; i < 4; ++i)
        #pragma unroll
        for (int j = 0; j < 8; ++j) acc2[i][j] = (f32x4)0.f;
    #pragma unroll
    for (int ks = 0; ks < 8; ++ks) {
        short8 af2[4];
        #pragma unroll
        for (int mf = 0; mf < 4; ++mf)
            af2[mf] = *(const short8*)(lds + ks * 8192 + a2 + mf * 256);
        #pragma unroll
        for (int nf = 0; nf < 8; ++nf) {
            const short8 bq = *(const short8*)(Qp4 + (size_t)ks * 32768 + qoff[nf]);
            #pragma unroll
            for (int mf = 0; mf < 4; ++mf)
                acc2[mf][nf] = __builtin_amdgcn_mfma_f32_16x16x32_bf16(af2[mf], bq, acc2[mf][nf], 0, 0, 0);
        }
    }

    // ---- epilogue (R2-proven, clean 64MB writes): 4 passes via ep LDS ----
#define LBAR { SB asm volatile("s_waitcnt lgkmcnt(0)\n\ts_barrier" ::: "memory"); SB }
    #pragma unroll
    for (int mh = 0; mh < 4; ++mh) {
        LBAR
        if (wm == (mh >> 1)) {
            #pragma unroll
            for (int mfh = 0; mfh < 2; ++mfh) {
                const int mf = (mh & 1) * 2 + mfh;
                #pragma unroll
                for (int q = 0; q < 4; ++q) {
                    const int oc = ochalf * 64 + q * 16 + lr;
                    const int ub = si * 34816 + oc * 272 + (((4 * mfh + kg) ^ (oc & 7)) << 5);
                    // w = 32*mfh + 8*kg + 2*r + sj ; sj=0 -> nf=q, sj=1 -> nf=4+q
                    f32x4 v0 = { acc2[mf][q][0], acc2[mf][4 + q][0], acc2[mf][q][1], acc2[mf][4 + q][1] };
                    f32x4 v1 = { acc2[mf][q][2], acc2[mf][4 + q][2], acc2[mf][q][3], acc2[mf][4 + q][3] };
                    *(f32x4*)(lds + ub) = v0;
                    *(f32x4*)(lds + ub + 16) = v1;
                }
            }
        }
        LBAR
        #pragma unroll
        for (int it = 0; it < 8; ++it) {
            int uidx = it * 512 + tid;
            int w4 = uidx & 15, oc = (uidx >> 4) & 127, sie = uidx >> 11;
            f32x4 v = *(const f32x4*)(lds + sie * 34816 + oc * 272 + ((w4 ^ (2 * (oc & 7))) << 4));
            *(f32x4*)(out + (size_t)n * 524288 + (size_t)oc * 4096
                          + (8 * vt + 2 * mh + sie) * 64 + w4 * 4) = v;
        }
    }
}

extern "C" void kernel_launch(void* const* d_in, const int* in_sizes, int n_in,
                              void* d_out, int out_size, void* d_ws, size_t ws_size,
                              hipStream_t stream) {
    const float* x = (const float*)d_in[0];
    const float* Q = (const float*)d_in[1];
    const float* R = (const float*)d_in[2];
    float* out = (float*)d_out;

    char* ws = (char*)d_ws;
    char* Rp4 = ws;
    char* Qp4 = ws + QB_OFF;
    char* xph = ws + XPH_OFF;

    prep_kernel<<<2368, 256, 0, stream>>>(x, Q, R, Rp4, Qp4, xph);
    fused_kernel<<<256, 512, 122880, stream>>>(xph, Rp4, Qp4, out);
}